// Round 1
// baseline (1744.741 us; speedup 1.0000x reference)
//
#include <hip/hip_runtime.h>

#define IMGS   32
#define HW     512
#define NPIX   (HW*HW)
#define NTOT   (IMGS*NPIX)
#define TW     64
#define TH     16

__device__ __forceinline__ float wave_reduce_sum(float v) {
    #pragma unroll
    for (int off = 32; off > 0; off >>= 1) v += __shfl_down(v, off);
    return v;
}

// ---------------- min/max normalization ----------------
__global__ __launch_bounds__(256) void minmax_partial(
    const float4* __restrict__ x, float* __restrict__ pmin, float* __restrict__ pmax)
{
    const int n4 = NTOT / 4;
    int tid = threadIdx.x + blockIdx.x * 256;
    int stride = gridDim.x * 256;
    float mn = 3.402823466e38f, mx = -3.402823466e38f;
    for (int i = tid; i < n4; i += stride) {
        float4 v = x[i];
        mn = fminf(mn, fminf(fminf(v.x, v.y), fminf(v.z, v.w)));
        mx = fmaxf(mx, fmaxf(fmaxf(v.x, v.y), fmaxf(v.z, v.w)));
    }
    #pragma unroll
    for (int off = 32; off > 0; off >>= 1) {
        mn = fminf(mn, __shfl_down(mn, off));
        mx = fmaxf(mx, __shfl_down(mx, off));
    }
    __shared__ float smn[4], smx[4];
    int lane = threadIdx.x & 63, wid = threadIdx.x >> 6;
    if (lane == 0) { smn[wid] = mn; smx[wid] = mx; }
    __syncthreads();
    if (threadIdx.x == 0) {
        mn = fminf(fminf(smn[0], smn[1]), fminf(smn[2], smn[3]));
        mx = fmaxf(fmaxf(smx[0], smx[1]), fmaxf(smx[2], smx[3]));
        pmin[blockIdx.x] = mn;
        pmax[blockIdx.x] = mx;
    }
}

__global__ __launch_bounds__(256) void minmax_final(
    const float* __restrict__ pmin, const float* __restrict__ pmax,
    float* __restrict__ scal, int nparts)
{
    float mn = 3.402823466e38f, mx = -3.402823466e38f;
    for (int i = threadIdx.x; i < nparts; i += 256) {
        mn = fminf(mn, pmin[i]);
        mx = fmaxf(mx, pmax[i]);
    }
    #pragma unroll
    for (int off = 32; off > 0; off >>= 1) {
        mn = fminf(mn, __shfl_down(mn, off));
        mx = fmaxf(mx, __shfl_down(mx, off));
    }
    __shared__ float smn[4], smx[4];
    int lane = threadIdx.x & 63, wid = threadIdx.x >> 6;
    if (lane == 0) { smn[wid] = mn; smx[wid] = mx; }
    __syncthreads();
    if (threadIdx.x == 0) {
        mn = fminf(fminf(smn[0], smn[1]), fminf(smn[2], smn[3]));
        mx = fmaxf(fmaxf(smx[0], smx[1]), fmaxf(smx[2], smx[3]));
        scal[0] = mn;
        scal[1] = 1.0f / (mx - mn);
    }
}

__global__ __launch_bounds__(256) void normalize_k(
    const float4* __restrict__ x, float4* __restrict__ y, const float* __restrict__ scal)
{
    const int n4 = NTOT / 4;
    float mn = scal[0], inv = scal[1];
    int tid = threadIdx.x + blockIdx.x * 256;
    int stride = gridDim.x * 256;
    for (int i = tid; i < n4; i += stride) {
        float4 v = x[i];
        v.x = (v.x - mn) * inv;
        v.y = (v.y - mn) * inv;
        v.z = (v.z - mn) * inv;
        v.w = (v.w - mn) * inv;
        y[i] = v;
    }
}

// ---------------- fused dual-conv layer step ----------------
// out = relu( scale*conv(xin,wx) + conv(y,wy) + (bx+by) )
// optionally writes per-block partial sums of outputs.
__global__ __launch_bounds__(256) void conv_step(
    const float* __restrict__ xin, const float* __restrict__ yin,
    const float* __restrict__ wx, const float* __restrict__ wy,
    const float* __restrict__ bxp, const float* __restrict__ byp,
    const float* __restrict__ scale_p,
    float* __restrict__ out, float* __restrict__ sumPartials)
{
    __shared__ __align__(16) float xs[TH + 4][TW + 4];
    __shared__ __align__(16) float ys[TH + 4][TW + 4];

    const int img   = blockIdx.z;
    const int tileX = blockIdx.x * TW;
    const int tileY = blockIdx.y * TH;
    const int tid   = threadIdx.x;

    const float* __restrict__ xim = xin + (size_t)img * NPIX;
    const float* __restrict__ yim = yin + (size_t)img * NPIX;

    // stage x and y tiles with 2-px halo (zero padding at image borders)
    for (int i = tid; i < (TH + 4) * (TW + 4); i += 256) {
        int r = i / (TW + 4);
        int c = i - r * (TW + 4);
        int gr = tileY + r - 2;
        int gc = tileX + c - 2;
        bool ok = (gr >= 0) & (gr < HW) & (gc >= 0) & (gc < HW);
        size_t gi = (size_t)gr * HW + gc;
        xs[r][c] = ok ? xim[gi] : 0.0f;
        ys[r][c] = ok ? yim[gi] : 0.0f;
    }
    __syncthreads();

    // uniform loads -> scalar regs
    float wxr[25], wyr[25];
    #pragma unroll
    for (int k = 0; k < 25; ++k) { wxr[k] = wx[k]; wyr[k] = wy[k]; }
    const float bias  = bxp[0] + byp[0];
    const float scale = scale_p ? scale_p[0] : 1.0f;

    const int tx = tid & 15;   // column group: cols 4*tx .. 4*tx+3
    const int ty = tid >> 4;   // output row within tile

    float accx[4] = {0.f, 0.f, 0.f, 0.f};
    float accy[4] = {0.f, 0.f, 0.f, 0.f};

    #pragma unroll
    for (int di = 0; di < 5; ++di) {
        const float4 a0 = *(const float4*)&xs[ty + di][4 * tx];
        const float4 a1 = *(const float4*)&xs[ty + di][4 * tx + 4];
        const float xw[8] = {a0.x, a0.y, a0.z, a0.w, a1.x, a1.y, a1.z, a1.w};
        const float4 b0 = *(const float4*)&ys[ty + di][4 * tx];
        const float4 b1 = *(const float4*)&ys[ty + di][4 * tx + 4];
        const float yw[8] = {b0.x, b0.y, b0.z, b0.w, b1.x, b1.y, b1.z, b1.w};
        #pragma unroll
        for (int dj = 0; dj < 5; ++dj) {
            const float wa = wxr[di * 5 + dj];
            const float wb = wyr[di * 5 + dj];
            #pragma unroll
            for (int o = 0; o < 4; ++o) {
                accx[o] = fmaf(xw[o + dj], wa, accx[o]);
                accy[o] = fmaf(yw[o + dj], wb, accy[o]);
            }
        }
    }

    float4 res;
    res.x = fmaxf(fmaf(scale, accx[0], accy[0]) + bias, 0.0f);
    res.y = fmaxf(fmaf(scale, accx[1], accy[1]) + bias, 0.0f);
    res.z = fmaxf(fmaf(scale, accx[2], accy[2]) + bias, 0.0f);
    res.w = fmaxf(fmaf(scale, accx[3], accy[3]) + bias, 0.0f);

    float* orow = out + (size_t)img * NPIX + (size_t)(tileY + ty) * HW + tileX + 4 * tx;
    *(float4*)orow = res;

    if (sumPartials) {
        float s = (res.x + res.y) + (res.z + res.w);
        s = wave_reduce_sum(s);
        __shared__ float ssum[4];
        int lane = tid & 63, wid = tid >> 6;
        if (lane == 0) ssum[wid] = s;
        __syncthreads();
        if (tid == 0) {
            int bidx = (blockIdx.z * gridDim.y + blockIdx.y) * gridDim.x + blockIdx.x;
            sumPartials[bidx] = (ssum[0] + ssum[1]) + (ssum[2] + ssum[3]);
        }
    }
}

__global__ __launch_bounds__(256) void reduce_sum(
    const float* __restrict__ p, int n, float* __restrict__ invS)
{
    float s = 0.0f;
    for (int i = threadIdx.x; i < n; i += 256) s += p[i];
    s = wave_reduce_sum(s);
    __shared__ float sh[4];
    int lane = threadIdx.x & 63, wid = threadIdx.x >> 6;
    if (lane == 0) sh[wid] = s;
    __syncthreads();
    if (threadIdx.x == 0) invS[0] = 1.0f / ((sh[0] + sh[1]) + (sh[2] + sh[3]));
}

__global__ __launch_bounds__(256) void final_scale(
    float4* __restrict__ io, const float* __restrict__ invS)
{
    const int n4 = NTOT / 4;
    const float s = invS[0];
    int tid = threadIdx.x + blockIdx.x * 256;
    int stride = gridDim.x * 256;
    for (int i = tid; i < n4; i += stride) {
        float4 v = io[i];
        v.x *= s; v.y *= s; v.z *= s; v.w *= s;
        io[i] = v;
    }
}

extern "C" void kernel_launch(void* const* d_in, const int* in_sizes, int n_in,
                              void* d_out, int out_size, void* d_ws, size_t ws_size,
                              hipStream_t stream)
{
    const float* x  = (const float*)d_in[0];
    const float* Wx = (const float*)d_in[1];
    const float* bx = (const float*)d_in[2];
    const float* Wy = (const float*)d_in[3];
    const float* by = (const float*)d_in[4];
    float* out = (float*)d_out;
    float* ws  = (float*)d_ws;

    // workspace layout (floats)
    float* scal  = ws;            // [0]=min, [1]=1/(max-min)
    float* invS  = ws + 2;        // 10 slots, one per iteration
    float* pmin  = ws + 16;       // 1024
    float* pmax  = ws + 16 + 1024;
    float* spart = ws + 4096;     // 8192 block partial sums
    float* ybuf  = ws + 16384;    // NTOT floats (normalized input, fixed)
    float* xA    = ybuf + NTOT;   // NTOT floats (ping buffer; d_out is pong)

    minmax_partial<<<1024, 256, 0, stream>>>((const float4*)x, pmin, pmax);
    minmax_final<<<1, 256, 0, stream>>>(pmin, pmax, scal, 1024);
    normalize_k<<<2048, 256, 0, stream>>>((const float4*)x, (float4*)ybuf, scal);

    dim3 grid(HW / TW, HW / TH, IMGS);  // (8, 32, 32) = 8192 blocks
    const float* cur = ybuf;
    for (int it = 0; it < 10; ++it) {
        for (int l = 0; l < 5; ++l) {
            int s = it * 5 + l;
            float* dst = (s % 2 == 0) ? xA : out;          // step 49 (odd) -> out
            const float* scale_p = (l == 0 && it > 0) ? (invS + (it - 1)) : nullptr;
            float* sp = (l == 4) ? spart : nullptr;
            conv_step<<<grid, 256, 0, stream>>>(
                cur, ybuf, Wx + 25 * l, Wy + 25 * l, bx + l, by + l,
                scale_p, dst, sp);
            cur = dst;
            if (l == 4)
                reduce_sum<<<1, 256, 0, stream>>>(spart, 8192, invS + it);
        }
    }
    // final division lands in d_out (in place)
    final_scale<<<2048, 256, 0, stream>>>((float4*)out, invS + 9);
}

// Round 2
// 1408.848 us; speedup vs baseline: 1.2384x; 1.2384x over previous
//
#include <hip/hip_runtime.h>

#define HW    512
#define NPIX  (HW*HW)
#define IMGS  32
#define NTOT  (IMGS*NPIX)

// fused-iteration tile: 64x32 output, halo 10 (5 layers x 2)
#define TLW 64
#define TLH 32
#define SW  84   // TLW + 20
#define SH  52   // TLH + 20

__device__ __forceinline__ float wave_reduce_sum(float v) {
    #pragma unroll
    for (int off = 32; off > 0; off >>= 1) v += __shfl_down(v, off);
    return v;
}

// ---------------- prologue: global min-max normalization ----------------
__global__ __launch_bounds__(256) void minmax_partial(
    const float4* __restrict__ x, float* __restrict__ pmin, float* __restrict__ pmax)
{
    const int n4 = NTOT / 4;
    int tid = threadIdx.x + blockIdx.x * 256;
    int stride = gridDim.x * 256;
    float mn = 3.402823466e38f, mx = -3.402823466e38f;
    for (int i = tid; i < n4; i += stride) {
        float4 v = x[i];
        mn = fminf(mn, fminf(fminf(v.x, v.y), fminf(v.z, v.w)));
        mx = fmaxf(mx, fmaxf(fmaxf(v.x, v.y), fmaxf(v.z, v.w)));
    }
    #pragma unroll
    for (int off = 32; off > 0; off >>= 1) {
        mn = fminf(mn, __shfl_down(mn, off));
        mx = fmaxf(mx, __shfl_down(mx, off));
    }
    __shared__ float smn[4], smx[4];
    int lane = threadIdx.x & 63, wid = threadIdx.x >> 6;
    if (lane == 0) { smn[wid] = mn; smx[wid] = mx; }
    __syncthreads();
    if (threadIdx.x == 0) {
        mn = fminf(fminf(smn[0], smn[1]), fminf(smn[2], smn[3]));
        mx = fmaxf(fmaxf(smx[0], smx[1]), fmaxf(smx[2], smx[3]));
        pmin[blockIdx.x] = mn;
        pmax[blockIdx.x] = mx;
    }
}

__global__ __launch_bounds__(256) void minmax_final(
    const float* __restrict__ pmin, const float* __restrict__ pmax,
    float* __restrict__ scal, int nparts)
{
    float mn = 3.402823466e38f, mx = -3.402823466e38f;
    for (int i = threadIdx.x; i < nparts; i += 256) {
        mn = fminf(mn, pmin[i]);
        mx = fmaxf(mx, pmax[i]);
    }
    #pragma unroll
    for (int off = 32; off > 0; off >>= 1) {
        mn = fminf(mn, __shfl_down(mn, off));
        mx = fmaxf(mx, __shfl_down(mx, off));
    }
    __shared__ float smn[4], smx[4];
    int lane = threadIdx.x & 63, wid = threadIdx.x >> 6;
    if (lane == 0) { smn[wid] = mn; smx[wid] = mx; }
    __syncthreads();
    if (threadIdx.x == 0) {
        mn = fminf(fminf(smn[0], smn[1]), fminf(smn[2], smn[3]));
        mx = fmaxf(fmaxf(smx[0], smx[1]), fmaxf(smx[2], smx[3]));
        scal[0] = mn;
        scal[1] = 1.0f / (mx - mn);
    }
}

__global__ __launch_bounds__(256) void normalize_k(
    const float4* __restrict__ x, float4* __restrict__ y, const float* __restrict__ scal)
{
    const int n4 = NTOT / 4;
    float mn = scal[0], inv = scal[1];
    int tid = threadIdx.x + blockIdx.x * 256;
    int stride = gridDim.x * 256;
    for (int i = tid; i < n4; i += stride) {
        float4 v = x[i];
        v.x = (v.x - mn) * inv;
        v.y = (v.y - mn) * inv;
        v.z = (v.z - mn) * inv;
        v.w = (v.w - mn) * inv;
        y[i] = v;
    }
}

// ---------------- one conv layer inside the fused kernel ----------------
// Input region WIN x HIN (0-based, stride WIN) in LDS; output (WIN-4)x(HIN-4).
// Each active thread computes a 4x4 register block via an 8-row sliding window.
// Non-last layers MUST write exact 0 at out-of-image positions (they act as
// the next layer's zero padding).  Last layer writes the 64x32 tile to global
// and returns this thread's partial sum.
template<int WIN, int HIN, int L, bool LAST>
__device__ __forceinline__ float conv_layer(
    const float* __restrict__ inb, float* __restrict__ outb,
    const float* __restrict__ yb,
    const float* __restrict__ Wx, const float* __restrict__ Wy,
    const float* __restrict__ bx, const float* __restrict__ by,
    float* __restrict__ gout, int img, int tileX, int tileY)
{
    constexpr int WOUT = WIN - 4, HOUT = HIN - 4;
    constexpr int NBC = WOUT / 4, NBR = HOUT / 4, NB = NBC * NBR;
    const int tid = threadIdx.x;
    float bsum = 0.0f;
    if (tid < NB) {
        float wxl[25], wyl[25];
        #pragma unroll
        for (int k = 0; k < 25; ++k) {
            wxl[k] = Wx[25 * L + k];
            wyl[k] = Wy[25 * L + k];
        }
        const float bias = bx[L] + by[L];
        const int br = tid / NBC, bc = tid - (tid / NBC) * NBC;
        const float* xp = inb + (4 * br) * WIN + 4 * bc;
        const float* yp = yb + (4 * br + 2 * L) * SW + 4 * bc + 2 * L;

        float acc[4][4] = {};
        #pragma unroll
        for (int di = 0; di < 8; ++di) {
            float xr[8], yr[8];
            *(float4*)&xr[0] = *(const float4*)(xp + di * WIN);
            *(float4*)&xr[4] = *(const float4*)(xp + di * WIN + 4);
            if constexpr ((L & 1) == 0) {
                *(float4*)&yr[0] = *(const float4*)(yp + di * SW);
                *(float4*)&yr[4] = *(const float4*)(yp + di * SW + 4);
            } else {  // y window shifted by 2 floats -> b64/b128/b64 aligned reads
                *(float2*)&yr[0] = *(const float2*)(yp + di * SW);
                *(float4*)&yr[2] = *(const float4*)(yp + di * SW + 2);
                *(float2*)&yr[6] = *(const float2*)(yp + di * SW + 6);
            }
            #pragma unroll
            for (int o = 0; o < 4; ++o) {
                const int ki = di - o;
                if (ki >= 0 && ki <= 4) {   // folds at compile time (di,o unrolled)
                    #pragma unroll
                    for (int kj = 0; kj < 5; ++kj) {
                        const float wa = wxl[ki * 5 + kj];
                        const float wb = wyl[ki * 5 + kj];
                        #pragma unroll
                        for (int j = 0; j < 4; ++j)
                            acc[o][j] = fmaf(xr[kj + j], wa,
                                        fmaf(yr[kj + j], wb, acc[o][j]));
                    }
                }
            }
        }

        if constexpr (LAST) {
            // output region == tile, always fully in-image
            #pragma unroll
            for (int o = 0; o < 4; ++o) {
                float4 v;
                v.x = fmaxf(acc[o][0] + bias, 0.0f);
                v.y = fmaxf(acc[o][1] + bias, 0.0f);
                v.z = fmaxf(acc[o][2] + bias, 0.0f);
                v.w = fmaxf(acc[o][3] + bias, 0.0f);
                float* g = gout + (size_t)img * NPIX +
                           (size_t)(tileY + 4 * br + o) * HW + tileX + 4 * bc;
                *(float4*)g = v;
                bsum += (v.x + v.y) + (v.z + v.w);
            }
        } else {
            const int gy0 = tileY - 8 + 2 * L + 4 * br;  // global row of acc[0]
            const int gx0 = tileX - 8 + 2 * L + 4 * bc;  // global col of acc[.][0]
            bool cok[4];
            #pragma unroll
            for (int j = 0; j < 4; ++j) cok[j] = (unsigned)(gx0 + j) < HW;
            #pragma unroll
            for (int o = 0; o < 4; ++o) {
                const bool rok = (unsigned)(gy0 + o) < HW;
                float4 v;
                v.x = (rok && cok[0]) ? fmaxf(acc[o][0] + bias, 0.0f) : 0.0f;
                v.y = (rok && cok[1]) ? fmaxf(acc[o][1] + bias, 0.0f) : 0.0f;
                v.z = (rok && cok[2]) ? fmaxf(acc[o][2] + bias, 0.0f) : 0.0f;
                v.w = (rok && cok[3]) ? fmaxf(acc[o][3] + bias, 0.0f) : 0.0f;
                *(float4*)(outb + (4 * br + o) * WOUT + 4 * bc) = v;
            }
        }
    }
    (void)img; (void)gout;
    return bsum;
}

// ---------------- fused 5-layer iteration kernel ----------------
// out = L4(L3(L2(L1(L0(scale*xin, y), y), y), y), y); per-block partial sums.
__global__ __launch_bounds__(256, 3) void fused5(
    const float* __restrict__ xin, const float* __restrict__ yin,
    const float* __restrict__ Wx, const float* __restrict__ bx,
    const float* __restrict__ Wy, const float* __restrict__ by,
    const float* __restrict__ scale_p,
    float* __restrict__ gout, float* __restrict__ spart)
{
    __shared__ __align__(16) float Xa[SW * SH];               // 84x52
    __shared__ __align__(16) float Xb[(SW - 4) * (SH - 4)];   // 80x48
    __shared__ __align__(16) float Yb[SW * SH];               // 84x52

    const int img = blockIdx.z;
    const int tileX = blockIdx.x * TLW;
    const int tileY = blockIdx.y * TLH;
    const int tid = threadIdx.x;

    const float scale = scale_p ? scale_p[0] : 1.0f;
    const float* xim = xin + (size_t)img * NPIX;
    const float* yim = yin + (size_t)img * NPIX;

    // stage x (scaled) and y with halo, zero outside image; float2 (8B) loads
    constexpr int NPAIR = SW * SH / 2;   // 2184
    for (int p = tid; p < NPAIR; p += 256) {
        int row = p / (SW / 2);
        int cp  = p - row * (SW / 2);
        int gr = tileY - 10 + row;
        int gc = tileX - 10 + 2 * cp;
        float2 xv = make_float2(0.f, 0.f), yv = make_float2(0.f, 0.f);
        if (((unsigned)gr < HW) & ((unsigned)gc < HW)) {
            xv = *(const float2*)(xim + (size_t)gr * HW + gc);
            yv = *(const float2*)(yim + (size_t)gr * HW + gc);
        }
        Xa[2 * p]     = xv.x * scale;
        Xa[2 * p + 1] = xv.y * scale;
        *(float2*)&Yb[2 * p] = yv;
    }
    __syncthreads();

    conv_layer<SW,      SH,      0, false>(Xa, Xb, Yb, Wx, Wy, bx, by, nullptr, img, tileX, tileY);
    __syncthreads();
    conv_layer<SW - 4,  SH - 4,  1, false>(Xb, Xa, Yb, Wx, Wy, bx, by, nullptr, img, tileX, tileY);
    __syncthreads();
    conv_layer<SW - 8,  SH - 8,  2, false>(Xa, Xb, Yb, Wx, Wy, bx, by, nullptr, img, tileX, tileY);
    __syncthreads();
    conv_layer<SW - 12, SH - 12, 3, false>(Xb, Xa, Yb, Wx, Wy, bx, by, nullptr, img, tileX, tileY);
    __syncthreads();
    float bs = conv_layer<SW - 16, SH - 16, 4, true>(Xa, nullptr, Yb, Wx, Wy, bx, by, gout, img, tileX, tileY);

    // per-block partial sum of this iteration's output
    bs = wave_reduce_sum(bs);
    __shared__ float ssum[4];
    if ((tid & 63) == 0) ssum[tid >> 6] = bs;
    __syncthreads();
    if (tid == 0) {
        int b = (blockIdx.z * gridDim.y + blockIdx.y) * gridDim.x + blockIdx.x;
        spart[b] = (ssum[0] + ssum[1]) + (ssum[2] + ssum[3]);
    }
}

__global__ __launch_bounds__(256) void reduce_sum(
    const float* __restrict__ p, int n, float* __restrict__ invS)
{
    float s = 0.0f;
    for (int i = threadIdx.x; i < n; i += 256) s += p[i];
    s = wave_reduce_sum(s);
    __shared__ float sh[4];
    int lane = threadIdx.x & 63, wid = threadIdx.x >> 6;
    if (lane == 0) sh[wid] = s;
    __syncthreads();
    if (threadIdx.x == 0) invS[0] = 1.0f / ((sh[0] + sh[1]) + (sh[2] + sh[3]));
}

__global__ __launch_bounds__(256) void final_scale(
    float4* __restrict__ io, const float* __restrict__ invS)
{
    const int n4 = NTOT / 4;
    const float s = invS[0];
    int tid = threadIdx.x + blockIdx.x * 256;
    int stride = gridDim.x * 256;
    for (int i = tid; i < n4; i += stride) {
        float4 v = io[i];
        v.x *= s; v.y *= s; v.z *= s; v.w *= s;
        io[i] = v;
    }
}

extern "C" void kernel_launch(void* const* d_in, const int* in_sizes, int n_in,
                              void* d_out, int out_size, void* d_ws, size_t ws_size,
                              hipStream_t stream)
{
    const float* x  = (const float*)d_in[0];
    const float* Wx = (const float*)d_in[1];
    const float* bx = (const float*)d_in[2];
    const float* Wy = (const float*)d_in[3];
    const float* by = (const float*)d_in[4];
    float* out = (float*)d_out;
    float* ws  = (float*)d_ws;

    // workspace layout (floats)
    float* scal  = ws;             // [0]=min, [1]=1/(max-min)
    float* invS  = ws + 2;         // 10 slots, one per iteration
    float* pmin  = ws + 16;        // 1024
    float* pmax  = ws + 16 + 1024;
    float* spart = ws + 4096;      // 4096 block partial sums
    float* ybuf  = ws + 16384;     // NTOT (normalized input, fixed)
    float* xA    = ybuf + NTOT;    // NTOT (ping buffer; d_out is pong)

    minmax_partial<<<1024, 256, 0, stream>>>((const float4*)x, pmin, pmax);
    minmax_final<<<1, 256, 0, stream>>>(pmin, pmax, scal, 1024);
    normalize_k<<<2048, 256, 0, stream>>>((const float4*)x, (float4*)ybuf, scal);

    dim3 grid(HW / TLW, HW / TLH, IMGS);   // (8, 16, 32) = 4096 blocks
    const float* cur = ybuf;
    for (int it = 0; it < 10; ++it) {
        float* dst = (it % 2 == 0) ? xA : out;   // it 9 (odd) -> out
        const float* scale_p = (it > 0) ? (invS + (it - 1)) : nullptr;
        fused5<<<grid, 256, 0, stream>>>(cur, ybuf, Wx, bx, Wy, by, scale_p, dst, spart);
        reduce_sum<<<1, 256, 0, stream>>>(spart, 4096, invS + it);
        cur = dst;
    }
    final_scale<<<2048, 256, 0, stream>>>((float4*)out, invS + 9);
}

// Round 3
// 1086.636 us; speedup vs baseline: 1.6056x; 1.2965x over previous
//
#include <hip/hip_runtime.h>

#define HW    512
#define NPIX  (HW*HW)
#define IMGS  32
#define NTOT  (IMGS*NPIX)

// fused-iteration tile: 64x32 output, halo 10 (5 layers x 2)
#define TLW 64
#define TLH 32
#define SW  84   // TLW + 20
#define SH  52   // TLH + 20

// prep tile (normalize + Yc precompute): 64x64, halo 2
#define PT  64
#define PS  68

__device__ __forceinline__ float wave_reduce_sum(float v) {
    #pragma unroll
    for (int off = 32; off > 0; off >>= 1) v += __shfl_down(v, off);
    return v;
}

// ---------------- prologue: global min-max ----------------
__global__ __launch_bounds__(256) void minmax_partial(
    const float4* __restrict__ x, float* __restrict__ pmin, float* __restrict__ pmax)
{
    const int n4 = NTOT / 4;
    int tid = threadIdx.x + blockIdx.x * 256;
    int stride = gridDim.x * 256;
    float mn = 3.402823466e38f, mx = -3.402823466e38f;
    for (int i = tid; i < n4; i += stride) {
        float4 v = x[i];
        mn = fminf(mn, fminf(fminf(v.x, v.y), fminf(v.z, v.w)));
        mx = fmaxf(mx, fmaxf(fmaxf(v.x, v.y), fmaxf(v.z, v.w)));
    }
    #pragma unroll
    for (int off = 32; off > 0; off >>= 1) {
        mn = fminf(mn, __shfl_down(mn, off));
        mx = fmaxf(mx, __shfl_down(mx, off));
    }
    __shared__ float smn[4], smx[4];
    int lane = threadIdx.x & 63, wid = threadIdx.x >> 6;
    if (lane == 0) { smn[wid] = mn; smx[wid] = mx; }
    __syncthreads();
    if (threadIdx.x == 0) {
        mn = fminf(fminf(smn[0], smn[1]), fminf(smn[2], smn[3]));
        mx = fmaxf(fmaxf(smx[0], smx[1]), fmaxf(smx[2], smx[3]));
        pmin[blockIdx.x] = mn;
        pmax[blockIdx.x] = mx;
    }
}

__global__ __launch_bounds__(256) void minmax_final(
    const float* __restrict__ pmin, const float* __restrict__ pmax,
    float* __restrict__ scal, int nparts)
{
    float mn = 3.402823466e38f, mx = -3.402823466e38f;
    for (int i = threadIdx.x; i < nparts; i += 256) {
        mn = fminf(mn, pmin[i]);
        mx = fmaxf(mx, pmax[i]);
    }
    #pragma unroll
    for (int off = 32; off > 0; off >>= 1) {
        mn = fminf(mn, __shfl_down(mn, off));
        mx = fmaxf(mx, __shfl_down(mx, off));
    }
    __shared__ float smn[4], smx[4];
    int lane = threadIdx.x & 63, wid = threadIdx.x >> 6;
    if (lane == 0) { smn[wid] = mn; smx[wid] = mx; }
    __syncthreads();
    if (threadIdx.x == 0) {
        mn = fminf(fminf(smn[0], smn[1]), fminf(smn[2], smn[3]));
        mx = fmaxf(fmaxf(smx[0], smx[1]), fmaxf(smx[2], smx[3]));
        scal[0] = mn;
        scal[1] = 1.0f / (mx - mn);
    }
}

__global__ __launch_bounds__(256) void normalize_k(
    const float4* __restrict__ x, float4* __restrict__ y, const float* __restrict__ scal)
{
    const int n4 = NTOT / 4;
    float mn = scal[0], inv = scal[1];
    int tid = threadIdx.x + blockIdx.x * 256;
    int stride = gridDim.x * 256;
    for (int i = tid; i < n4; i += stride) {
        float4 v = x[i];
        v.x = (v.x - mn) * inv;
        v.y = (v.y - mn) * inv;
        v.z = (v.z - mn) * inv;
        v.w = (v.w - mn) * inv;
        y[i] = v;
    }
}

// ---------------- prep: normalize + precompute Yc[l] = conv(y,Wy[l]) + bx[l]+by[l] ----------------
__global__ __launch_bounds__(256) void prep(
    const float* __restrict__ x, const float* __restrict__ scal,
    const float* __restrict__ bx,
    const float* __restrict__ Wy, const float* __restrict__ by,
    float* __restrict__ ybuf, float* __restrict__ Yc)
{
    __shared__ __align__(16) float ys[PS * PS];   // 68x68 = 18.5 KB

    const int img = blockIdx.z;
    const int tileX = blockIdx.x * PT;
    const int tileY = blockIdx.y * PT;
    const int tid = threadIdx.x;
    const float mn = scal[0], inv = scal[1];
    const float* xim = x + (size_t)img * NPIX;

    // stage normalized y with halo 2; exact 0 outside image (zero padding)
    for (int p = tid; p < PS * PS / 2; p += 256) {
        int row = p / (PS / 2);
        int cp  = p - row * (PS / 2);
        int gr = tileY - 2 + row;
        int gc = tileX - 2 + 2 * cp;        // even; pairs never straddle the border
        float a = 0.f, b = 0.f;
        if (((unsigned)gr < HW) & ((unsigned)gc < HW)) {
            float2 v = *(const float2*)(xim + (size_t)gr * HW + gc);
            a = (v.x - mn) * inv;
            b = (v.y - mn) * inv;
        }
        ys[row * PS + 2 * cp]     = a;
        ys[row * PS + 2 * cp + 1] = b;
    }
    __syncthreads();

    // write y tile to global (from LDS)
    for (int p = tid; p < PT * PT / 2; p += 256) {
        int row = p / (PT / 2);
        int cp  = p - row * (PT / 2);
        float2 v = *(const float2*)&ys[(row + 2) * PS + 2 * cp + 2];
        *(float2*)(ybuf + (size_t)img * NPIX + (size_t)(tileY + row) * HW + tileX + 2 * cp) = v;
    }

    // each thread: 4x4 output block, 5 convs over the staged y window
    const int br = tid >> 4, bc = tid & 15;
    const float* yp = ys + (4 * br) * PS + 4 * bc;

    #pragma unroll
    for (int l = 0; l < 5; ++l) {
        float w[25];
        #pragma unroll
        for (int k = 0; k < 25; ++k) w[k] = Wy[25 * l + k];
        const float bias = bx[l] + by[l];

        float acc[4][4] = {};
        #pragma unroll
        for (int di = 0; di < 8; ++di) {
            float xr[8];
            *(float4*)&xr[0] = *(const float4*)(yp + di * PS);
            *(float4*)&xr[4] = *(const float4*)(yp + di * PS + 4);
            #pragma unroll
            for (int o = 0; o < 4; ++o) {
                const int ki = di - o;
                if (ki >= 0 && ki <= 4) {
                    #pragma unroll
                    for (int kj = 0; kj < 5; ++kj) {
                        const float wa = w[ki * 5 + kj];
                        #pragma unroll
                        for (int j = 0; j < 4; ++j)
                            acc[o][j] = fmaf(xr[kj + j], wa, acc[o][j]);
                    }
                }
            }
        }
        float* yl = Yc + (size_t)l * NTOT + (size_t)img * NPIX;
        #pragma unroll
        for (int o = 0; o < 4; ++o) {
            float4 v;
            v.x = acc[o][0] + bias;
            v.y = acc[o][1] + bias;
            v.z = acc[o][2] + bias;
            v.w = acc[o][3] + bias;
            *(float4*)(yl + (size_t)(tileY + 4 * br + o) * HW + tileX + 4 * bc) = v;
        }
    }
}

// ---------------- one x-conv layer, adds precomputed Yc ----------------
template<int WIN, int HIN, int L, bool LAST>
__device__ __forceinline__ float conv_layer_yc(
    const float* __restrict__ inb, float* __restrict__ outb,
    const float* __restrict__ Wx, const float* __restrict__ ycim,
    float* __restrict__ gout, int img, int tileX, int tileY)
{
    constexpr int WOUT = WIN - 4, HOUT = HIN - 4;
    constexpr int NBC = WOUT / 4, NBR = HOUT / 4, NB = NBC * NBR;
    const int tid = threadIdx.x;
    float bsum = 0.0f;
    if (tid < NB) {
        float w[25];
        #pragma unroll
        for (int k = 0; k < 25; ++k) w[k] = Wx[25 * L + k];
        const int br = tid / NBC, bc = tid - (tid / NBC) * NBC;
        const float* xp = inb + (4 * br) * WIN + 4 * bc;

        float acc[4][4] = {};
        #pragma unroll
        for (int di = 0; di < 8; ++di) {
            float xr[8];
            *(float4*)&xr[0] = *(const float4*)(xp + di * WIN);
            *(float4*)&xr[4] = *(const float4*)(xp + di * WIN + 4);
            #pragma unroll
            for (int o = 0; o < 4; ++o) {
                const int ki = di - o;
                if (ki >= 0 && ki <= 4) {
                    #pragma unroll
                    for (int kj = 0; kj < 5; ++kj) {
                        const float wa = w[ki * 5 + kj];
                        #pragma unroll
                        for (int j = 0; j < 4; ++j)
                            acc[o][j] = fmaf(xr[kj + j], wa, acc[o][j]);
                    }
                }
            }
        }

        if constexpr (LAST) {
            #pragma unroll
            for (int o = 0; o < 4; ++o) {
                const int gy = tileY + 4 * br + o;
                const float4 yc = *(const float4*)(ycim + (size_t)gy * HW + tileX + 4 * bc);
                float4 v;
                v.x = fmaxf(acc[o][0] + yc.x, 0.0f);
                v.y = fmaxf(acc[o][1] + yc.y, 0.0f);
                v.z = fmaxf(acc[o][2] + yc.z, 0.0f);
                v.w = fmaxf(acc[o][3] + yc.w, 0.0f);
                *(float4*)(gout + (size_t)img * NPIX + (size_t)gy * HW + tileX + 4 * bc) = v;
                bsum += (v.x + v.y) + (v.z + v.w);
            }
        } else {
            const int gy0 = tileY - 8 + 2 * L + 4 * br;
            const int gx0 = tileX - 8 + 2 * L + 4 * bc;
            bool cok[4];
            #pragma unroll
            for (int j = 0; j < 4; ++j) cok[j] = (unsigned)(gx0 + j) < HW;
            const bool fullc = (gx0 >= 0) & (gx0 + 3 < HW);
            #pragma unroll
            for (int o = 0; o < 4; ++o) {
                const bool rok = (unsigned)(gy0 + o) < HW;
                float yv[4] = {0.f, 0.f, 0.f, 0.f};
                if (rok) {
                    const float* p = ycim + (size_t)(gy0 + o) * HW + gx0;
                    if (fullc) {
                        if constexpr ((2 * L) % 4 == 0) {       // 16B-aligned
                            *(float4*)yv = *(const float4*)p;
                        } else {                                 // 8B-aligned
                            *(float2*)&yv[0] = *(const float2*)p;
                            *(float2*)&yv[2] = *(const float2*)(p + 2);
                        }
                    } else {
                        #pragma unroll
                        for (int j = 0; j < 4; ++j) if (cok[j]) yv[j] = p[j];
                    }
                }
                float4 v;
                v.x = (rok && cok[0]) ? fmaxf(acc[o][0] + yv[0], 0.0f) : 0.0f;
                v.y = (rok && cok[1]) ? fmaxf(acc[o][1] + yv[1], 0.0f) : 0.0f;
                v.z = (rok && cok[2]) ? fmaxf(acc[o][2] + yv[2], 0.0f) : 0.0f;
                v.w = (rok && cok[3]) ? fmaxf(acc[o][3] + yv[3], 0.0f) : 0.0f;
                *(float4*)(outb + (4 * br + o) * WOUT + 4 * bc) = v;
            }
        }
    }
    (void)img; (void)gout;
    return bsum;
}

// ---------------- fused 5-layer iteration kernel (Yc path) ----------------
__global__ __launch_bounds__(256, 4) void fused5_yc(
    const float* __restrict__ xin, const float* __restrict__ Wx,
    const float* __restrict__ Yc, const float* __restrict__ scale_p,
    float* __restrict__ gout, float* __restrict__ spart)
{
    __shared__ __align__(16) float Xa[SW * SH];               // 84x52
    __shared__ __align__(16) float Xb[(SW - 4) * (SH - 4)];   // 80x48

    const int img = blockIdx.z;
    const int tileX = blockIdx.x * TLW;
    const int tileY = blockIdx.y * TLH;
    const int tid = threadIdx.x;

    const float scale = scale_p ? scale_p[0] : 1.0f;
    const float* xim = xin + (size_t)img * NPIX;
    const float* ycb = Yc + (size_t)img * NPIX;

    // stage scaled x with halo 10, exact 0 outside image
    constexpr int NPAIR = SW * SH / 2;
    for (int p = tid; p < NPAIR; p += 256) {
        int row = p / (SW / 2);
        int cp  = p - row * (SW / 2);
        int gr = tileY - 10 + row;
        int gc = tileX - 10 + 2 * cp;
        float a = 0.f, b = 0.f;
        if (((unsigned)gr < HW) & ((unsigned)gc < HW)) {
            float2 v = *(const float2*)(xim + (size_t)gr * HW + gc);
            a = v.x * scale;
            b = v.y * scale;
        }
        Xa[2 * p]     = a;
        Xa[2 * p + 1] = b;
    }
    __syncthreads();

    conv_layer_yc<SW,      SH,      0, false>(Xa, Xb, Wx, ycb + 0 * (size_t)IMGS * NPIX, nullptr, img, tileX, tileY);
    __syncthreads();
    conv_layer_yc<SW - 4,  SH - 4,  1, false>(Xb, Xa, Wx, ycb + 1 * (size_t)IMGS * NPIX, nullptr, img, tileX, tileY);
    __syncthreads();
    conv_layer_yc<SW - 8,  SH - 8,  2, false>(Xa, Xb, Wx, ycb + 2 * (size_t)IMGS * NPIX, nullptr, img, tileX, tileY);
    __syncthreads();
    conv_layer_yc<SW - 12, SH - 12, 3, false>(Xb, Xa, Wx, ycb + 3 * (size_t)IMGS * NPIX, nullptr, img, tileX, tileY);
    __syncthreads();
    float bs = conv_layer_yc<SW - 16, SH - 16, 4, true>(Xa, nullptr, Wx, ycb + 4 * (size_t)IMGS * NPIX, gout, img, tileX, tileY);

    bs = wave_reduce_sum(bs);
    __shared__ float ssum[4];
    if ((tid & 63) == 0) ssum[tid >> 6] = bs;
    __syncthreads();
    if (tid == 0) {
        int b = (blockIdx.z * gridDim.y + blockIdx.y) * gridDim.x + blockIdx.x;
        spart[b] = (ssum[0] + ssum[1]) + (ssum[2] + ssum[3]);
    }
}

// ---------------- fallback: round-2 dual-conv fused kernel ----------------
template<int WIN, int HIN, int L, bool LAST>
__device__ __forceinline__ float conv_layer(
    const float* __restrict__ inb, float* __restrict__ outb,
    const float* __restrict__ yb,
    const float* __restrict__ Wx, const float* __restrict__ Wy,
    const float* __restrict__ bx, const float* __restrict__ by,
    float* __restrict__ gout, int img, int tileX, int tileY)
{
    constexpr int WOUT = WIN - 4, HOUT = HIN - 4;
    constexpr int NBC = WOUT / 4, NBR = HOUT / 4, NB = NBC * NBR;
    const int tid = threadIdx.x;
    float bsum = 0.0f;
    if (tid < NB) {
        float wxl[25], wyl[25];
        #pragma unroll
        for (int k = 0; k < 25; ++k) {
            wxl[k] = Wx[25 * L + k];
            wyl[k] = Wy[25 * L + k];
        }
        const float bias = bx[L] + by[L];
        const int br = tid / NBC, bc = tid - (tid / NBC) * NBC;
        const float* xp = inb + (4 * br) * WIN + 4 * bc;
        const float* yp = yb + (4 * br + 2 * L) * SW + 4 * bc + 2 * L;

        float acc[4][4] = {};
        #pragma unroll
        for (int di = 0; di < 8; ++di) {
            float xr[8], yr[8];
            *(float4*)&xr[0] = *(const float4*)(xp + di * WIN);
            *(float4*)&xr[4] = *(const float4*)(xp + di * WIN + 4);
            if constexpr ((L & 1) == 0) {
                *(float4*)&yr[0] = *(const float4*)(yp + di * SW);
                *(float4*)&yr[4] = *(const float4*)(yp + di * SW + 4);
            } else {
                *(float2*)&yr[0] = *(const float2*)(yp + di * SW);
                *(float4*)&yr[2] = *(const float4*)(yp + di * SW + 2);
                *(float2*)&yr[6] = *(const float2*)(yp + di * SW + 6);
            }
            #pragma unroll
            for (int o = 0; o < 4; ++o) {
                const int ki = di - o;
                if (ki >= 0 && ki <= 4) {
                    #pragma unroll
                    for (int kj = 0; kj < 5; ++kj) {
                        const float wa = wxl[ki * 5 + kj];
                        const float wb = wyl[ki * 5 + kj];
                        #pragma unroll
                        for (int j = 0; j < 4; ++j)
                            acc[o][j] = fmaf(xr[kj + j], wa,
                                        fmaf(yr[kj + j], wb, acc[o][j]));
                    }
                }
            }
        }

        if constexpr (LAST) {
            #pragma unroll
            for (int o = 0; o < 4; ++o) {
                float4 v;
                v.x = fmaxf(acc[o][0] + bias, 0.0f);
                v.y = fmaxf(acc[o][1] + bias, 0.0f);
                v.z = fmaxf(acc[o][2] + bias, 0.0f);
                v.w = fmaxf(acc[o][3] + bias, 0.0f);
                float* g = gout + (size_t)img * NPIX +
                           (size_t)(tileY + 4 * br + o) * HW + tileX + 4 * bc;
                *(float4*)g = v;
                bsum += (v.x + v.y) + (v.z + v.w);
            }
        } else {
            const int gy0 = tileY - 8 + 2 * L + 4 * br;
            const int gx0 = tileX - 8 + 2 * L + 4 * bc;
            bool cok[4];
            #pragma unroll
            for (int j = 0; j < 4; ++j) cok[j] = (unsigned)(gx0 + j) < HW;
            #pragma unroll
            for (int o = 0; o < 4; ++o) {
                const bool rok = (unsigned)(gy0 + o) < HW;
                float4 v;
                v.x = (rok && cok[0]) ? fmaxf(acc[o][0] + bias, 0.0f) : 0.0f;
                v.y = (rok && cok[1]) ? fmaxf(acc[o][1] + bias, 0.0f) : 0.0f;
                v.z = (rok && cok[2]) ? fmaxf(acc[o][2] + bias, 0.0f) : 0.0f;
                v.w = (rok && cok[3]) ? fmaxf(acc[o][3] + bias, 0.0f) : 0.0f;
                *(float4*)(outb + (4 * br + o) * WOUT + 4 * bc) = v;
            }
        }
    }
    (void)img; (void)gout;
    return bsum;
}

__global__ __launch_bounds__(256, 3) void fused5(
    const float* __restrict__ xin, const float* __restrict__ yin,
    const float* __restrict__ Wx, const float* __restrict__ bx,
    const float* __restrict__ Wy, const float* __restrict__ by,
    const float* __restrict__ scale_p,
    float* __restrict__ gout, float* __restrict__ spart)
{
    __shared__ __align__(16) float Xa[SW * SH];
    __shared__ __align__(16) float Xb[(SW - 4) * (SH - 4)];
    __shared__ __align__(16) float Yb[SW * SH];

    const int img = blockIdx.z;
    const int tileX = blockIdx.x * TLW;
    const int tileY = blockIdx.y * TLH;
    const int tid = threadIdx.x;

    const float scale = scale_p ? scale_p[0] : 1.0f;
    const float* xim = xin + (size_t)img * NPIX;
    const float* yim = yin + (size_t)img * NPIX;

    constexpr int NPAIR = SW * SH / 2;
    for (int p = tid; p < NPAIR; p += 256) {
        int row = p / (SW / 2);
        int cp  = p - row * (SW / 2);
        int gr = tileY - 10 + row;
        int gc = tileX - 10 + 2 * cp;
        float2 xv = make_float2(0.f, 0.f), yv = make_float2(0.f, 0.f);
        if (((unsigned)gr < HW) & ((unsigned)gc < HW)) {
            xv = *(const float2*)(xim + (size_t)gr * HW + gc);
            yv = *(const float2*)(yim + (size_t)gr * HW + gc);
        }
        Xa[2 * p]     = xv.x * scale;
        Xa[2 * p + 1] = xv.y * scale;
        *(float2*)&Yb[2 * p] = yv;
    }
    __syncthreads();

    conv_layer<SW,      SH,      0, false>(Xa, Xb, Yb, Wx, Wy, bx, by, nullptr, img, tileX, tileY);
    __syncthreads();
    conv_layer<SW - 4,  SH - 4,  1, false>(Xb, Xa, Yb, Wx, Wy, bx, by, nullptr, img, tileX, tileY);
    __syncthreads();
    conv_layer<SW - 8,  SH - 8,  2, false>(Xa, Xb, Yb, Wx, Wy, bx, by, nullptr, img, tileX, tileY);
    __syncthreads();
    conv_layer<SW - 12, SH - 12, 3, false>(Xb, Xa, Yb, Wx, Wy, bx, by, nullptr, img, tileX, tileY);
    __syncthreads();
    float bs = conv_layer<SW - 16, SH - 16, 4, true>(Xa, nullptr, Yb, Wx, Wy, bx, by, gout, img, tileX, tileY);

    bs = wave_reduce_sum(bs);
    __shared__ float ssum[4];
    if ((tid & 63) == 0) ssum[tid >> 6] = bs;
    __syncthreads();
    if (tid == 0) {
        int b = (blockIdx.z * gridDim.y + blockIdx.y) * gridDim.x + blockIdx.x;
        spart[b] = (ssum[0] + ssum[1]) + (ssum[2] + ssum[3]);
    }
}

__global__ __launch_bounds__(256) void reduce_sum(
    const float* __restrict__ p, int n, float* __restrict__ invS)
{
    float s = 0.0f;
    for (int i = threadIdx.x; i < n; i += 256) s += p[i];
    s = wave_reduce_sum(s);
    __shared__ float sh[4];
    int lane = threadIdx.x & 63, wid = threadIdx.x >> 6;
    if (lane == 0) sh[wid] = s;
    __syncthreads();
    if (threadIdx.x == 0) invS[0] = 1.0f / ((sh[0] + sh[1]) + (sh[2] + sh[3]));
}

__global__ __launch_bounds__(256) void final_scale(
    float4* __restrict__ io, const float* __restrict__ invS)
{
    const int n4 = NTOT / 4;
    const float s = invS[0];
    int tid = threadIdx.x + blockIdx.x * 256;
    int stride = gridDim.x * 256;
    for (int i = tid; i < n4; i += stride) {
        float4 v = io[i];
        v.x *= s; v.y *= s; v.z *= s; v.w *= s;
        io[i] = v;
    }
}

extern "C" void kernel_launch(void* const* d_in, const int* in_sizes, int n_in,
                              void* d_out, int out_size, void* d_ws, size_t ws_size,
                              hipStream_t stream)
{
    const float* x  = (const float*)d_in[0];
    const float* Wx = (const float*)d_in[1];
    const float* bx = (const float*)d_in[2];
    const float* Wy = (const float*)d_in[3];
    const float* by = (const float*)d_in[4];
    float* out = (float*)d_out;
    float* ws  = (float*)d_ws;

    // workspace layout (floats)
    float* scal  = ws;             // [0]=min, [1]=1/(max-min)
    float* invS  = ws + 2;         // 10 slots, one per iteration
    float* pmin  = ws + 16;        // 1024
    float* pmax  = ws + 16 + 1024;
    float* spart = ws + 4096;      // 4096 block partial sums
    float* ybuf  = ws + 16384;     // NTOT (normalized input, fixed)
    float* xA    = ybuf + NTOT;    // NTOT (ping buffer; d_out is pong)
    float* Yc    = xA + NTOT;      // 5*NTOT (precomputed y-conv planes)

    const size_t needYC = ((size_t)16384 + 7ull * NTOT) * sizeof(float);

    minmax_partial<<<1024, 256, 0, stream>>>((const float4*)x, pmin, pmax);
    minmax_final<<<1, 256, 0, stream>>>(pmin, pmax, scal, 1024);

    if (ws_size >= needYC) {
        // --- Yc path: y-conv precomputed once ---
        dim3 pgrid(HW / PT, HW / PT, IMGS);            // (8, 8, 32)
        prep<<<pgrid, 256, 0, stream>>>(x, scal, bx, Wy, by, ybuf, Yc);

        dim3 grid(HW / TLW, HW / TLH, IMGS);           // (8, 16, 32)
        const float* cur = ybuf;
        for (int it = 0; it < 10; ++it) {
            float* dst = (it % 2 == 0) ? xA : out;     // it 9 (odd) -> out
            const float* scale_p = (it > 0) ? (invS + (it - 1)) : nullptr;
            fused5_yc<<<grid, 256, 0, stream>>>(cur, Wx, Yc, scale_p, dst, spart);
            reduce_sum<<<1, 256, 0, stream>>>(spart, 4096, invS + it);
            cur = dst;
        }
    } else {
        // --- fallback: round-2 dual-conv path ---
        normalize_k<<<2048, 256, 0, stream>>>((const float4*)x, (float4*)ybuf, scal);
        dim3 grid(HW / TLW, HW / TLH, IMGS);
        const float* cur = ybuf;
        for (int it = 0; it < 10; ++it) {
            float* dst = (it % 2 == 0) ? xA : out;
            const float* scale_p = (it > 0) ? (invS + (it - 1)) : nullptr;
            fused5<<<grid, 256, 0, stream>>>(cur, ybuf, Wx, bx, Wy, by, scale_p, dst, spart);
            reduce_sum<<<1, 256, 0, stream>>>(spart, 4096, invS + it);
            cur = dst;
        }
    }
    final_scale<<<2048, 256, 0, stream>>>((float4*)out, invS + 9);
}